// Round 1
// baseline (45.936 us; speedup 1.0000x reference)
//
#include <hip/hip_runtime.h>

// PewLSTM, HS=1: two stacked scalar LSTMs + scalar FC, fused into one kernel.
// B=32768 sequences, T=168 steps, 5 input channels (4 weather + 1 input).
// One thread per sequence; register double-buffered float4 input streaming.

constexpr int BB  = 32768;
constexpr int TT  = 168;
constexpr int CHS = 8;            // timesteps per chunk
constexpr int CHV = CHS * 5 / 4;  // 10 float4 per chunk (8*5=40 floats)
constexpr int NCH = TT / CHS;     // 21 chunks

#define LOG2E 1.44269504088896341f

__device__ __forceinline__ float sigf(float x) {
    // 1/(1+exp(-x)) via hw exp2 + rcp
    float e = __builtin_amdgcn_exp2f(-x * LOG2E);
    return __builtin_amdgcn_rcpf(1.0f + e);
}

__device__ __forceinline__ float tanh_fast(float x) {
    // tanh(x) = 2*sigmoid(2x) - 1
    float e = __builtin_amdgcn_exp2f(-x * (2.0f * LOG2E));
    return fmaf(2.0f, __builtin_amdgcn_rcpf(1.0f + e), -1.0f);
}

__global__ __launch_bounds__(64, 1) void pewlstm_kernel(
    const float* __restrict__ in,
    const float* __restrict__ W1ih, const float* __restrict__ W1hh,
    const float* __restrict__ W1wh, const float* __restrict__ b1,
    const float* __restrict__ W2ih, const float* __restrict__ W2hh,
    const float* __restrict__ W2wh, const float* __restrict__ b2,
    const float* __restrict__ fcw, const float* __restrict__ fcb,
    float* __restrict__ out)
{
    const int b = blockIdx.x * 64 + threadIdx.x;

    // tiny weights -> registers (broadcast loads, L1-resident)
    float w1ih[4], w1hh[4], bb1[4], w2ih[4], w2hh[4], bb2[4];
    float w1wh[16], w2wh[16];
#pragma unroll
    for (int g = 0; g < 4; ++g) {
        w1ih[g] = W1ih[g]; w1hh[g] = W1hh[g]; bb1[g] = b1[g];
        w2ih[g] = W2ih[g]; w2hh[g] = W2hh[g]; bb2[g] = b2[g];
    }
#pragma unroll
    for (int k = 0; k < 16; ++k) { w1wh[k] = W1wh[k]; w2wh[k] = W2wh[k]; }
    const float fw = fcw[0], fb = fcb[0];

    // per-thread row: 168*5 = 840 floats, contiguous; row stride 3360 B (16B aligned)
    const float4* __restrict__ row =
        reinterpret_cast<const float4*>(in + (size_t)b * (TT * 5));

    // prologue: prefetch chunk 0
    float4 pref[CHV];
#pragma unroll
    for (int i = 0; i < CHV; ++i) pref[i] = row[i];

    float h1 = 0.f, c1 = 0.f, h2 = 0.f, c2 = 0.f;

    for (int c = 0; c < NCH; ++c) {
        // commit prefetched chunk to a flat register array (static indices only)
        float cur[CHS * 5];
#pragma unroll
        for (int i = 0; i < CHV; ++i) {
            float4 v = pref[i];
            cur[4 * i + 0] = v.x; cur[4 * i + 1] = v.y;
            cur[4 * i + 2] = v.z; cur[4 * i + 3] = v.w;
        }
        // issue next chunk's loads now; consumed next iteration (~1300 cy away)
        if (c + 1 < NCH) {
            const float4* nrow = row + (c + 1) * CHV;
#pragma unroll
            for (int i = 0; i < CHV; ++i) pref[i] = nrow[i];
        }

        float ob[CHS];
#pragma unroll
        for (int s = 0; s < CHS; ++s) {
            const float xw0 = cur[s * 5 + 0];
            const float xw1 = cur[s * 5 + 1];
            const float xw2 = cur[s * 5 + 2];
            const float xw3 = cur[s * 5 + 3];
            const float xi  = cur[s * 5 + 4];

            // ---- layer 1 ----
            float ga1[4];
#pragma unroll
            for (int g = 0; g < 4; ++g) {
                float p = bb1[g];
                p = fmaf(xw0, w1wh[0 + g], p);
                p = fmaf(xw1, w1wh[4 + g], p);
                p = fmaf(xw2, w1wh[8 + g], p);
                p = fmaf(xw3, w1wh[12 + g], p);
                p = fmaf(xi,  w1ih[g], p);
                ga1[g] = fmaf(h1, w1hh[g], p);
            }
            const float i1 = sigf(ga1[0]);
            const float f1 = sigf(ga1[1]);
            const float g1 = tanh_fast(ga1[2]);
            const float o1 = sigf(ga1[3]);
            c1 = fmaf(f1, c1, i1 * g1);
            h1 = o1 * tanh_fast(c1);

            // ---- layer 2 (input = h1, same weather) ----
            float ga2[4];
#pragma unroll
            for (int g = 0; g < 4; ++g) {
                float p = bb2[g];
                p = fmaf(xw0, w2wh[0 + g], p);
                p = fmaf(xw1, w2wh[4 + g], p);
                p = fmaf(xw2, w2wh[8 + g], p);
                p = fmaf(xw3, w2wh[12 + g], p);
                p = fmaf(h1,  w2ih[g], p);
                ga2[g] = fmaf(h2, w2hh[g], p);
            }
            const float i2 = sigf(ga2[0]);
            const float f2 = sigf(ga2[1]);
            const float g2 = tanh_fast(ga2[2]);
            const float o2 = sigf(ga2[3]);
            c2 = fmaf(f2, c2, i2 * g2);
            h2 = o2 * tanh_fast(c2);

            ob[s] = fmaf(h2, fw, fb);
        }

        // out row offset b*168 floats = 672 B -> 16B aligned; 8 floats = 2 float4
        float4* orow = reinterpret_cast<float4*>(out + (size_t)b * TT + c * CHS);
#pragma unroll
        for (int i = 0; i < CHS / 4; ++i) {
            orow[i] = make_float4(ob[4 * i + 0], ob[4 * i + 1],
                                  ob[4 * i + 2], ob[4 * i + 3]);
        }
    }
}

extern "C" void kernel_launch(void* const* d_in, const int* in_sizes, int n_in,
                              void* d_out, int out_size, void* d_ws, size_t ws_size,
                              hipStream_t stream) {
    const float* in   = (const float*)d_in[0];
    const float* W1ih = (const float*)d_in[1];
    const float* W1hh = (const float*)d_in[2];
    const float* W1wh = (const float*)d_in[3];
    const float* b1   = (const float*)d_in[4];
    const float* W2ih = (const float*)d_in[5];
    const float* W2hh = (const float*)d_in[6];
    const float* W2wh = (const float*)d_in[7];
    const float* b2   = (const float*)d_in[8];
    const float* fcw  = (const float*)d_in[9];
    const float* fcb  = (const float*)d_in[10];
    float* out = (float*)d_out;

    pewlstm_kernel<<<BB / 64, 64, 0, stream>>>(
        in, W1ih, W1hh, W1wh, b1, W2ih, W2hh, W2wh, b2, fcw, fcb, out);
}

// Round 2
// 42.211 us; speedup vs baseline: 1.0883x; 1.0883x over previous
//
#include <hip/hip_runtime.h>

// PewLSTM HS=1, layer-pipelined across lane pairs.
// Even lane of each pair: LSTM layer 1 at step t.
// Odd  lane of each pair: LSTM layer 2 at step t-1 (1-step systolic lag).
// h1 handed off each step via __shfl_xor(h,1) (DPP quad-perm, no LDS).
// 65536 threads = 1024 waves -> 1 wave per SIMD on all 1024 SIMDs.

constexpr int BB  = 32768;
constexpr int TT  = 168;
constexpr int CHS = 8;            // timesteps per chunk
constexpr int CHV = CHS * 5 / 4;  // 10 float4 per chunk
constexpr int NCH = TT / CHS;     // 21 chunks

#define LOG2E 1.44269504088896341f

__device__ __forceinline__ float sigf(float x) {
    float e = __builtin_amdgcn_exp2f(-x * LOG2E);
    return __builtin_amdgcn_rcpf(1.0f + e);
}
__device__ __forceinline__ float tanh_fast(float x) {
    float e = __builtin_amdgcn_exp2f(-x * (2.0f * LOG2E));
    return fmaf(2.0f, __builtin_amdgcn_rcpf(1.0f + e), -1.0f);
}

__global__ __launch_bounds__(64, 1) void pewlstm_kernel(
    const float* __restrict__ in,
    const float* __restrict__ W1ih, const float* __restrict__ W1hh,
    const float* __restrict__ W1wh, const float* __restrict__ b1,
    const float* __restrict__ W2ih, const float* __restrict__ W2hh,
    const float* __restrict__ W2wh, const float* __restrict__ b2,
    const float* __restrict__ fcw, const float* __restrict__ fcb,
    float* __restrict__ out)
{
    const int tid = blockIdx.x * 64 + threadIdx.x;
    const int b   = tid >> 1;        // sequence index
    const int l2  = tid & 1;         // 1 = layer-2 lane

    // per-lane weight set (layer 1 or layer 2)
    const float* Wih = l2 ? W2ih : W1ih;
    const float* Whh = l2 ? W2hh : W1hh;
    const float* Wwh = l2 ? W2wh : W1wh;
    const float* Bv  = l2 ? b2   : b1;

    float wih[4], whh[4], bbv[4], wwh[16];
#pragma unroll
    for (int g = 0; g < 4; ++g) { wih[g] = Wih[g]; whh[g] = Whh[g]; bbv[g] = Bv[g]; }
#pragma unroll
    for (int k = 0; k < 16; ++k) wwh[k] = Wwh[k];
    const float fw = fcw[0], fbv = fcb[0];

    // both lanes of a pair stream the same contiguous row (840 floats, 16B aligned)
    const float4* __restrict__ row =
        reinterpret_cast<const float4*>(in + (size_t)b * (TT * 5));
    float4 pref[CHV];
#pragma unroll
    for (int i = 0; i < CHV; ++i) pref[i] = row[i];

    float h = 0.f, cc = 0.f;     // my layer's state
    float h1x = 0.f;             // h1(t) received from partner (odd lanes use it)
    float xo0 = 0.f, xo1 = 0.f, xo2 = 0.f, xo3 = 0.f;  // prev-step weather (odd lane)
    float ob[CHS];               // odd lane: buffered outputs
    float4* orow = reinterpret_cast<float4*>(out + (size_t)b * TT);

    for (int c = 0; c < NCH; ++c) {
        float cur[CHS * 5];
#pragma unroll
        for (int i = 0; i < CHV; ++i) {
            float4 v = pref[i];
            cur[4 * i + 0] = v.x; cur[4 * i + 1] = v.y;
            cur[4 * i + 2] = v.z; cur[4 * i + 3] = v.w;
        }
        if (c + 1 < NCH) {
            const float4* nrow = row + (c + 1) * CHV;
#pragma unroll
            for (int i = 0; i < CHV; ++i) pref[i] = nrow[i];
        }

#pragma unroll
        for (int s = 0; s < CHS; ++s) {
            const float xn0 = cur[s * 5 + 0];
            const float xn1 = cur[s * 5 + 1];
            const float xn2 = cur[s * 5 + 2];
            const float xn3 = cur[s * 5 + 3];
            const float xn4 = cur[s * 5 + 4];

            // my step's weather: even lane -> current step t; odd lane -> step t-1
            const float w0 = l2 ? xo0 : xn0;
            const float w1 = l2 ? xo1 : xn1;
            const float w2 = l2 ? xo2 : xn2;
            const float w3 = l2 ? xo3 : xn3;
            // my step's input: even -> x_input(t); odd -> h1(t-1) from partner
            const float inv = l2 ? h1x : xn4;

            float ga[4];
#pragma unroll
            for (int g = 0; g < 4; ++g) {
                float p = bbv[g];
                p = fmaf(w0, wwh[0 + g], p);
                p = fmaf(w1, wwh[4 + g], p);
                p = fmaf(w2, wwh[8 + g], p);
                p = fmaf(w3, wwh[12 + g], p);
                p = fmaf(inv, wih[g], p);
                ga[g] = fmaf(h, whh[g], p);
            }
            const float ig = sigf(ga[0]);
            const float fg = sigf(ga[1]);
            const float gg = tanh_fast(ga[2]);
            const float og = sigf(ga[3]);
            cc = fmaf(fg, cc, ig * gg);
            h  = og * tanh_fast(cc);

            // odd lane's phantom step at t=0 (it computed h2(-1)): reset state
            if (s == 0 && c == 0 && l2) { h = 0.f; cc = 0.f; }

            // odd lane holds h2(it-1) -> output slot (it-1) & 7
            ob[(s + CHS - 1) & (CHS - 1)] = fmaf(h, fw, fbv);

            // flush previous chunk's 8 outputs (steps (c-1)*8 .. c*8-1)
            if (s == 0 && c >= 1 && l2) {
                orow[(c - 1) * 2 + 0] = make_float4(ob[0], ob[1], ob[2], ob[3]);
                orow[(c - 1) * 2 + 1] = make_float4(ob[4], ob[5], ob[6], ob[7]);
            }

            // roll weather window; hand my h to partner (odd receives h1(t))
            xo0 = xn0; xo1 = xn1; xo2 = xn2; xo3 = xn3;
            h1x = __shfl_xor(h, 1, 64);
        }
    }

    // epilogue: iteration t=168 — odd lane computes h2(167); even result discarded
    {
        const float w0 = xo0, w1 = xo1, w2 = xo2, w3 = xo3;
        const float inv = h1x;
        float ga[4];
#pragma unroll
        for (int g = 0; g < 4; ++g) {
            float p = bbv[g];
            p = fmaf(w0, wwh[0 + g], p);
            p = fmaf(w1, wwh[4 + g], p);
            p = fmaf(w2, wwh[8 + g], p);
            p = fmaf(w3, wwh[12 + g], p);
            p = fmaf(inv, wih[g], p);
            ga[g] = fmaf(h, whh[g], p);
        }
        const float ig = sigf(ga[0]);
        const float fg = sigf(ga[1]);
        const float gg = tanh_fast(ga[2]);
        const float og = sigf(ga[3]);
        cc = fmaf(fg, cc, ig * gg);
        h  = og * tanh_fast(cc);
        ob[7] = fmaf(h, fw, fbv);
        if (l2) {
            orow[(NCH - 1) * 2 + 0] = make_float4(ob[0], ob[1], ob[2], ob[3]);
            orow[(NCH - 1) * 2 + 1] = make_float4(ob[4], ob[5], ob[6], ob[7]);
        }
    }
}

extern "C" void kernel_launch(void* const* d_in, const int* in_sizes, int n_in,
                              void* d_out, int out_size, void* d_ws, size_t ws_size,
                              hipStream_t stream) {
    const float* in   = (const float*)d_in[0];
    const float* W1ih = (const float*)d_in[1];
    const float* W1hh = (const float*)d_in[2];
    const float* W1wh = (const float*)d_in[3];
    const float* b1   = (const float*)d_in[4];
    const float* W2ih = (const float*)d_in[5];
    const float* W2hh = (const float*)d_in[6];
    const float* W2wh = (const float*)d_in[7];
    const float* b2   = (const float*)d_in[8];
    const float* fcw  = (const float*)d_in[9];
    const float* fcb  = (const float*)d_in[10];
    float* out = (float*)d_out;

    // 2 lanes per sequence -> 65536 threads -> 1024 waves (1 per SIMD)
    pewlstm_kernel<<<(BB * 2) / 64, 64, 0, stream>>>(
        in, W1ih, W1hh, W1wh, b1, W2ih, W2hh, W2wh, b2, fcw, fcb, out);
}

// Round 3
// 32.520 us; speedup vs baseline: 1.4126x; 1.2980x over previous
//
#include <hip/hip_runtime.h>

// PewLSTM HS=1, layer-pipelined across lane pairs (even lane = layer 1 @ t,
// odd lane = layer 2 @ t-1), h1 handed off via DPP quad_perm lane swap.
// Per chunk: phase 1 computes all x-dependent gate pre-activations (parallel,
// fills stalls); phase 2 runs the short serial recurrence.

constexpr int BB  = 32768;
constexpr int TT  = 168;
constexpr int CHS = 8;            // timesteps per chunk
constexpr int CHV = CHS * 5 / 4;  // 10 float4 per chunk
constexpr int NCH = TT / CHS;     // 21 chunks

#define LOG2E 1.44269504088896341f

__device__ __forceinline__ float sigf(float x) {
    float e = __builtin_amdgcn_exp2f(-x * LOG2E);
    return __builtin_amdgcn_rcpf(1.0f + e);
}
__device__ __forceinline__ float tanh_fast(float x) {
    float e = __builtin_amdgcn_exp2f(-x * (2.0f * LOG2E));
    return fmaf(2.0f, __builtin_amdgcn_rcpf(1.0f + e), -1.0f);
}
// xor-1 lane swap as DPP quad_perm(1,0,3,2): VALU-latency, no LDS unit
__device__ __forceinline__ float lane_swap(float x) {
    return __int_as_float(
        __builtin_amdgcn_mov_dpp(__float_as_int(x), 0xB1, 0xF, 0xF, true));
}

__global__ __launch_bounds__(64, 1) void pewlstm_kernel(
    const float* __restrict__ in,
    const float* __restrict__ W1ih, const float* __restrict__ W1hh,
    const float* __restrict__ W1wh, const float* __restrict__ b1,
    const float* __restrict__ W2ih, const float* __restrict__ W2hh,
    const float* __restrict__ W2wh, const float* __restrict__ b2,
    const float* __restrict__ fcw, const float* __restrict__ fcb,
    float* __restrict__ out)
{
    const int tid = blockIdx.x * 64 + threadIdx.x;
    const int b   = tid >> 1;
    const int l2  = tid & 1;             // 1 = layer-2 lane
    const float l2f = l2 ? 1.0f : 0.0f;

    const float* Wih = l2 ? W2ih : W1ih;
    const float* Whh = l2 ? W2hh : W1hh;
    const float* Wwh = l2 ? W2wh : W1wh;
    const float* Bv  = l2 ? b2   : b1;

    float wih[4], whh[4], bbv[4], wwh[16];
#pragma unroll
    for (int g = 0; g < 4; ++g) { wih[g] = Wih[g]; whh[g] = Whh[g]; bbv[g] = Bv[g]; }
#pragma unroll
    for (int k = 0; k < 16; ++k) wwh[k] = Wwh[k];
    const float fw = fcw[0], fbv = fcb[0];

    const float4* __restrict__ row =
        reinterpret_cast<const float4*>(in + (size_t)b * (TT * 5));
    float4 pref[CHV];
#pragma unroll
    for (int i = 0; i < CHV; ++i) pref[i] = row[i];

    float h = 0.f, cc = 0.f;                       // my layer's state
    float h1x = 0.f;                               // partner's h1 (odd lanes)
    float xc0 = 0.f, xc1 = 0.f, xc2 = 0.f, xc3 = 0.f;  // prev chunk's last weather
    float ob[CHS];
    float4* orow = reinterpret_cast<float4*>(out + (size_t)b * TT);

    for (int c = 0; c < NCH; ++c) {
        float cur[CHS * 5];
#pragma unroll
        for (int i = 0; i < CHV; ++i) {
            float4 v = pref[i];
            cur[4 * i + 0] = v.x; cur[4 * i + 1] = v.y;
            cur[4 * i + 2] = v.z; cur[4 * i + 3] = v.w;
        }
        if (c + 1 < NCH) {
            const float4* nrow = row + (c + 1) * CHV;
#pragma unroll
            for (int i = 0; i < CHV; ++i) pref[i] = nrow[i];
        }

        // ---- phase 1: x-dependent gate pre-activations (no recurrence) ----
        float pre[CHS][4];
#pragma unroll
        for (int s = 0; s < CHS; ++s) {
            // even lane: weather(t=c*8+s); odd lane: weather(t-1)
            const float w0 = l2 ? (s == 0 ? xc0 : cur[(s - 1) * 5 + 0]) : cur[s * 5 + 0];
            const float w1 = l2 ? (s == 0 ? xc1 : cur[(s - 1) * 5 + 1]) : cur[s * 5 + 1];
            const float w2 = l2 ? (s == 0 ? xc2 : cur[(s - 1) * 5 + 2]) : cur[s * 5 + 2];
            const float w3 = l2 ? (s == 0 ? xc3 : cur[(s - 1) * 5 + 3]) : cur[s * 5 + 3];
            const float xi = l2 ? 0.0f : cur[s * 5 + 4];   // even: x_input folded here
#pragma unroll
            for (int g = 0; g < 4; ++g) {
                float p = bbv[g];
                p = fmaf(w0, wwh[0 + g], p);
                p = fmaf(w1, wwh[4 + g], p);
                p = fmaf(w2, wwh[8 + g], p);
                p = fmaf(w3, wwh[12 + g], p);
                pre[s][g] = fmaf(xi, wih[g], p);
            }
        }
        xc0 = cur[7 * 5 + 0]; xc1 = cur[7 * 5 + 1];
        xc2 = cur[7 * 5 + 2]; xc3 = cur[7 * 5 + 3];

        // ---- phase 2: serial recurrence (2 FMA + activations per gate) ----
#pragma unroll
        for (int s = 0; s < CHS; ++s) {
            const float inv = h1x * l2f;    // odd: h1(t-1); even: 0 (xi in pre)
            float ga[4];
#pragma unroll
            for (int g = 0; g < 4; ++g)
                ga[g] = fmaf(h, whh[g], fmaf(inv, wih[g], pre[s][g]));

            const float ig = sigf(ga[0]);
            const float fg = sigf(ga[1]);
            const float gg = tanh_fast(ga[2]);
            const float og = sigf(ga[3]);
            cc = fmaf(fg, cc, ig * gg);
            h  = og * tanh_fast(cc);

            if (s == 0 && c == 0 && l2) { h = 0.f; cc = 0.f; }  // phantom step reset

            ob[(s + CHS - 1) & (CHS - 1)] = fmaf(h, fw, fbv);

            if (s == 0 && c >= 1 && l2) {
                orow[(c - 1) * 2 + 0] = make_float4(ob[0], ob[1], ob[2], ob[3]);
                orow[(c - 1) * 2 + 1] = make_float4(ob[4], ob[5], ob[6], ob[7]);
            }

            h1x = lane_swap(h);             // hand h1 to partner (DPP, ~free)
        }
    }

    // ---- epilogue: iteration t=168 — odd lane computes h2(167) ----
    {
        float ga[4];
#pragma unroll
        for (int g = 0; g < 4; ++g) {
            float p = bbv[g];
            p = fmaf(xc0, wwh[0 + g], p);
            p = fmaf(xc1, wwh[4 + g], p);
            p = fmaf(xc2, wwh[8 + g], p);
            p = fmaf(xc3, wwh[12 + g], p);
            p = fmaf(h1x, wih[g], p);
            ga[g] = fmaf(h, whh[g], p);
        }
        const float ig = sigf(ga[0]);
        const float fg = sigf(ga[1]);
        const float gg = tanh_fast(ga[2]);
        const float og = sigf(ga[3]);
        cc = fmaf(fg, cc, ig * gg);
        h  = og * tanh_fast(cc);
        ob[7] = fmaf(h, fw, fbv);
        if (l2) {
            orow[(NCH - 1) * 2 + 0] = make_float4(ob[0], ob[1], ob[2], ob[3]);
            orow[(NCH - 1) * 2 + 1] = make_float4(ob[4], ob[5], ob[6], ob[7]);
        }
    }
}

extern "C" void kernel_launch(void* const* d_in, const int* in_sizes, int n_in,
                              void* d_out, int out_size, void* d_ws, size_t ws_size,
                              hipStream_t stream) {
    const float* in   = (const float*)d_in[0];
    const float* W1ih = (const float*)d_in[1];
    const float* W1hh = (const float*)d_in[2];
    const float* W1wh = (const float*)d_in[3];
    const float* b1   = (const float*)d_in[4];
    const float* W2ih = (const float*)d_in[5];
    const float* W2hh = (const float*)d_in[6];
    const float* W2wh = (const float*)d_in[7];
    const float* b2   = (const float*)d_in[8];
    const float* fcw  = (const float*)d_in[9];
    const float* fcb  = (const float*)d_in[10];
    float* out = (float*)d_out;

    pewlstm_kernel<<<(BB * 2) / 64, 64, 0, stream>>>(
        in, W1ih, W1hh, W1wh, b1, W2ih, W2hh, W2wh, b2, fcw, fcb, out);
}